// Round 17
// baseline (293.152 us; speedup 1.0000x reference)
//
#include <hip/hip_runtime.h>
#include <hip/hip_bf16.h>
#include <math.h>

// VectorQuantizer: z [8,256,32,32] f32, codebook [8192,256] f32
// outputs (flat f32): z_q [2097152] NCHW, idx [8192] (as float), loss, perplexity
#define KC 8192
#define DD 256
#define NP 8192
#define ZQ_ELEMS 2097152
#define MARGIN_S 1e-2f     // s-space (= 2e-2 d-space; fp16 E_max ~4.8e-3 d, 2x headroom)
#define NPART 8            // code-group partials (gemm grid.y)

// ws layout (bytes)
#define OFF_ABIG 0u           // f16 [8192][256]  points
#define OFF_BBIG 4194304u     // f16 [8192][256]  normalized codes
#define OFF_NRM  8388608u     // f32 [8192]
#define OFF_WSQ  8421376u     // f32 [8192]
#define OFF_PV1  8454144u     // f32 [8192][8]  (transposed partials)
#define OFF_PV2  8716288u     // f32 [8192][8]
#define OFF_PK1  8978432u     // i32 [8192][8]
#define OFF_LOSSP 9240576u    // f64 [512]
#define OFF_HIST 9244672u     // i32 [8192]
#define OFF_PACK 9277440u     // u64 [8192]
#define OFF_LIST 9342976u     // i32 [8192]
#define OFF_NFLG 9375744u     // i32 [1]

typedef __attribute__((ext_vector_type(8))) _Float16 f16x8;
typedef __attribute__((ext_vector_type(4))) float f32x4;
typedef __attribute__((address_space(3))) void as3_void;
typedef const __attribute__((address_space(1))) void as1_cvoid;

#define GLOAD16(g, l) __builtin_amdgcn_global_load_lds((as1_cvoid*)(g), (as3_void*)(l), 16, 0, 0)

__device__ inline double waveReduceD(double v) {
#pragma unroll
    for (int off = 32; off; off >>= 1) v += __shfl_down(v, off, 64);
    return v;
}

static __device__ inline unsigned short f2h(float f) {
    _Float16 h = (_Float16)f;  // RNE
    unsigned short u;
    __builtin_memcpy(&u, &h, 2);
    return u;
}

// fused prep:
//   blocks 0..2047: 4 codebook rows each (wave-per-row: normalize + f16 cast +
//                   wsq/nrm); blocks 0..31 zero hist; block 32 zeroes nflag
//   blocks 2048..2559: z tile-transpose (64d x 64hw, LDS-staged) + f16 cast
__global__ __launch_bounds__(256) void prep(
    const float* __restrict__ cb, const float* __restrict__ z,
    unsigned short* __restrict__ Bbig, unsigned short* __restrict__ Abig,
    float* __restrict__ nrm, float* __restrict__ wsq,
    int* __restrict__ hist, int* __restrict__ nflag) {
    int bid = blockIdx.x, t = threadIdx.x;
    int lane = t & 63, wid = t >> 6;
    if (bid < 2048) {
        if (bid < 32) hist[bid * 256 + t] = 0;
        if (bid == 32 && t == 0) *nflag = 0;
        int k = bid * 4 + wid;
        float4 c4 = *(const float4*)&cb[(size_t)k * DD + lane * 4];
        double s = (double)c4.x * c4.x + (double)c4.y * c4.y
                 + (double)c4.z * c4.z + (double)c4.w * c4.w;
#pragma unroll
        for (int off = 32; off; off >>= 1) s += __shfl_xor(s, off, 64);
        float mh = fmaxf(sqrtf((float)s), 1e-12f);
        if (lane == 0) {
            nrm[k] = mh;
            wsq[k] = (float)(s / ((double)mh * (double)mh));
        }
        *(ushort4*)&Bbig[(size_t)k * DD + lane * 4] =
            make_ushort4(f2h(c4.x / mh), f2h(c4.y / mh), f2h(c4.z / mh), f2h(c4.w / mh));
    } else {
        __shared__ float tile[64][65];
        int zb = bid - 2048;               // 0..511
        int b = zb >> 6, ht = (zb >> 2) & 15, dt = zb & 3;
        int hw0 = ht * 64, d0 = dt * 64;
#pragma unroll
        for (int i = 0; i < 16; ++i) {
            int dl = wid * 16 + i;
            tile[dl][lane] = z[(size_t)(b * DD + d0 + dl) * 1024 + hw0 + lane];
        }
        __syncthreads();
        // point row n = b*1024+hw0+nl needs z(d=d0+lane, hw=hw0+nl) == tile[lane][nl]
#pragma unroll
        for (int i = 0; i < 16; ++i) {
            int nl = wid * 16 + i;
            Abig[(size_t)(b * 1024 + hw0 + nl) * DD + d0 + lane] = f2h(tile[lane][nl]);
        }
    }
}

// Deep-pipelined MFMA GEMM + top-2 screen (R13 cadence, fp16 single-product).
// Quad-buffer, depth-3 staging, counted vmcnt, reg fragment ping-pong,
// 1 barrier/tile, single 32-tile sweep over 4 code-tiles (K=256 per ct).
// grid (32, 8) = 256 blocks = 1/CU. acc init = -wsq/2 => dv = -acc.
__global__ __launch_bounds__(512, 2) void gemm_top2(
    const unsigned short* __restrict__ Abig, const unsigned short* __restrict__ Bbig,
    const float* __restrict__ wsq,
    float* __restrict__ pv1, float* __restrict__ pv2, int* __restrict__ pk1) {
    __shared__ unsigned short sAB[65536];  // 4 bufs x [W 256x32 | Z 256x32] f16

    int t = threadIdx.x;
    int l = t & 63, w = t >> 6;
    int wm = w >> 2, wn = w & 3;
    int kc0 = blockIdx.y * 1024;  // this block's 1024-code range
    int n0 = blockIdx.x * 256;    // point base (C cols)

    int row0 = t >> 2;
    int lsw = (((t & 3) ^ ((row0 >> 1) & 3)) << 3);
    int subsw = (((l >> 4) ^ ((l >> 1) & 3)) << 3);

#define STAGE(g_) do {                                                         \
    int ct_ = (g_) >> 3;                                                       \
    int kt_ = (g_) & 7;                                                        \
    int off_ = kt_ * 32;                                                       \
    int b_ = ((g_) & 3) * 16384;                                               \
    int kc_ = kc0 + ct_ * 256;                                                 \
    GLOAD16(Bbig + (size_t)(kc_ + row0) * 256 + off_ + lsw, &sAB[b_ + t * 8]); \
    GLOAD16(Bbig + (size_t)(kc_ + row0 + 128) * 256 + off_ + lsw, &sAB[b_ + 4096 + t * 8]); \
    GLOAD16(Abig + (size_t)(n0 + row0) * 256 + off_ + lsw, &sAB[b_ + 8192 + t * 8]); \
    GLOAD16(Abig + (size_t)(n0 + row0 + 128) * 256 + off_ + lsw, &sAB[b_ + 12288 + t * 8]); \
} while (0)

#define LDFRAG(bufbase, fa, fb) do {                                           \
    _Pragma("unroll")                                                          \
    for (int mf = 0; mf < 8; ++mf)                                             \
        fa[mf] = *(const f16x8*)&sAB[(bufbase) + (wm * 128 + mf * 16 + (l & 15)) * 32 + subsw]; \
    _Pragma("unroll")                                                          \
    for (int nf = 0; nf < 4; ++nf)                                             \
        fb[nf] = *(const f16x8*)&sAB[(bufbase) + 8192 + (wn * 64 + nf * 16 + (l & 15)) * 32 + subsw]; \
} while (0)

#define MFMACL(fa, fb) do {                                                    \
    __builtin_amdgcn_s_setprio(1);                                             \
    _Pragma("unroll")                                                          \
    for (int mf = 0; mf < 8; ++mf)                                             \
        _Pragma("unroll")                                                      \
        for (int nf = 0; nf < 4; ++nf)                                         \
            acc[mf][nf] = __builtin_amdgcn_mfma_f32_16x16x32_f16(fa[mf], fb[nf], acc[mf][nf], 0, 0, 0); \
    __builtin_amdgcn_s_setprio(0);                                             \
} while (0)

#define WAITBAR(n_) do {                                                       \
    asm volatile("s_waitcnt vmcnt(" #n_ ")" ::: "memory");                     \
    __builtin_amdgcn_s_barrier();                                              \
    asm volatile("" ::: "memory");                                             \
} while (0)

#define RESETACC(ct_) do {                                                     \
    _Pragma("unroll")                                                          \
    for (int mf = 0; mf < 8; ++mf) {                                           \
        _Pragma("unroll")                                                      \
        for (int r = 0; r < 4; ++r) {                                          \
            float hv = -0.5f * wsq[kc0 + (ct_) * 256 + wm * 128 + mf * 16 + ((l >> 4) << 2) + r]; \
            _Pragma("unroll")                                                  \
            for (int nf = 0; nf < 4; ++nf) acc[mf][nf][r] = hv;                \
        }                                                                      \
    }                                                                          \
} while (0)

#define EXTRACT(ct_) do {                                                      \
    _Pragma("unroll")                                                          \
    for (int mf = 0; mf < 8; ++mf) {                                           \
        _Pragma("unroll")                                                      \
        for (int r = 0; r < 4; ++r) {                                          \
            int code = kc0 + (ct_) * 256 + wm * 128 + mf * 16 + ((l >> 4) << 2) + r; \
            _Pragma("unroll")                                                  \
            for (int nf = 0; nf < 4; ++nf) {                                   \
                float dv = -acc[mf][nf][r];                                    \
                bool lt = dv < v1[nf];                                         \
                v2[nf] = fminf(v2[nf], fmaxf(v1[nf], dv));                     \
                v1[nf] = fminf(v1[nf], dv);                                    \
                k1[nf] = lt ? code : k1[nf];                                   \
            }                                                                  \
        }                                                                      \
    }                                                                          \
} while (0)

    float v1[4], v2[4];
    int k1[4];
#pragma unroll
    for (int nf = 0; nf < 4; ++nf) { v1[nf] = 3.4e38f; v2[nf] = 3.4e38f; k1[nf] = 0; }

    f32x4 acc[8][4];
    RESETACC(0);

    f16x8 fa0[8], fb0[4], fa1[8], fb1[4];

    // prologue: stage tiles 0,1,2; tile 0 resident (8 loads stay in flight)
    STAGE(0);
    STAGE(1);
    STAGE(2);
    WAITBAR(8);
    LDFRAG(0, fa0, fb0);

    // 32-tile loop (tiles 0..29 here; 30,31 in tail). Boundary extracts at
    // tile 7/15/23 (ct 0/1/2); ct 3 extracted in tail.
    for (int g = 0; g < 30; g += 2) {
        WAITBAR(4);                               // tile g+1 resident
        LDFRAG(((g + 1) & 3) * 16384, fa1, fb1);
        STAGE(g + 3);                             // g <= 28 -> g+3 <= 31
        MFMACL(fa0, fb0);                         // tile g
        WAITBAR(4);                               // tile g+2 resident
        LDFRAG(((g + 2) & 3) * 16384, fa0, fb0);
        if (g < 28) STAGE(g + 4);
        MFMACL(fa1, fb1);                         // tile g+1
        if (((g + 1) & 7) == 7) {
            int ct = (g + 1) >> 3;
            EXTRACT(ct);
            RESETACC(ct + 1);                     // ct < 3 always here
        }
    }
    // tail: tiles 30, 31
    WAITBAR(0);                                   // tile 31 resident
    LDFRAG(3 * 16384, fa1, fb1);
    MFMACL(fa0, fb0);                             // tile 30
    MFMACL(fa1, fb1);                             // tile 31
    EXTRACT(3);

    // merge across the 4 row-groups (lanes l, l^16, l^32, l^48 share cols)
#pragma unroll
    for (int nf = 0; nf < 4; ++nf) {
#pragma unroll
        for (int mask = 16; mask <= 32; mask <<= 1) {
            float ov1 = __shfl_xor(v1[nf], mask, 64);
            float ov2 = __shfl_xor(v2[nf], mask, 64);
            int ok1 = __shfl_xor(k1[nf], mask, 64);
            bool take = (ov1 < v1[nf]) || (ov1 == v1[nf] && ok1 < k1[nf]);
            if (take) { v2[nf] = fminf(v1[nf], ov2); v1[nf] = ov1; k1[nf] = ok1; }
            else v2[nf] = fminf(v2[nf], ov1);
        }
    }
    __syncthreads();  // pipeline fully done; reuse LDS for cross-wave merge
    float* sv1 = (float*)sAB;            // [256][2]
    float* sv2 = sv1 + 512;
    int* sk1 = (int*)(sv2 + 512);
    if ((l >> 4) == 0) {
#pragma unroll
        for (int nf = 0; nf < 4; ++nf) {
            int col = wn * 64 + nf * 16 + l;
            sv1[col * 2 + wm] = v1[nf];
            sv2[col * 2 + wm] = v2[nf];
            sk1[col * 2 + wm] = k1[nf];
        }
    }
    __syncthreads();
    if (t < 256) {
        float a1 = sv1[t * 2], b1 = sv1[t * 2 + 1];
        float a2 = sv2[t * 2], b2 = sv2[t * 2 + 1];
        int ak = sk1[t * 2], bk = sk1[t * 2 + 1];
        bool tb = (b1 < a1) || (b1 == a1 && bk < ak);
        float w1 = tb ? b1 : a1;
        int wk = tb ? bk : ak;
        float w2 = tb ? fminf(b2, a1) : fminf(a2, b1);
        pv1[(size_t)(n0 + t) * NPART + blockIdx.y] = w1;
        pv2[(size_t)(n0 + t) * NPART + blockIdx.y] = w2;
        pk1[(size_t)(n0 + t) * NPART + blockIdx.y] = wk;
    }
#undef STAGE
#undef LDFRAG
#undef MFMACL
#undef WAITBAR
#undef RESETACC
#undef EXTRACT
}

// merge 8 partials per point (contiguous); packed holds winner k (or ~0
// sentinel for flagged rows, which rescore_par atomicMin-fills exactly)
__global__ __launch_bounds__(256) void merge_top2(
    const float* __restrict__ pv1, const float* __restrict__ pv2,
    const int* __restrict__ pk1, int* __restrict__ list, int* __restrict__ nflag,
    unsigned long long* __restrict__ packed) {
    int n = blockIdx.x * 256 + threadIdx.x;
    float gv1 = 3.4e38f, gv2 = 3.4e38f;
    int gk1 = 0;
#pragma unroll
    for (int ct = 0; ct < NPART; ++ct) {
        float v1 = pv1[(size_t)n * NPART + ct];
        if (v1 < gv1) {
            gv2 = fminf(gv1, pv2[(size_t)n * NPART + ct]);
            gv1 = v1;
            gk1 = pk1[(size_t)n * NPART + ct];
        } else {
            gv2 = fminf(gv2, v1);
        }
    }
    int f = (gv2 - gv1 < MARGIN_S) ? 1 : 0;
    packed[n] = f ? 0xFFFFFFFFFFFFFFFFull : (unsigned long long)(unsigned)gk1;
    if (f) {
        int pos = atomicAdd(nflag, 1);
        list[pos] = n;
    }
}

// exact fp32 rescore of flagged rows, wave-cooperative (lanes along D).
__global__ __launch_bounds__(256) void rescore_par(
    const float* __restrict__ z, const float* __restrict__ cb,
    const float* __restrict__ nrm, const float* __restrict__ wsq,
    const int* __restrict__ list, const int* __restrict__ nflag,
    unsigned long long* __restrict__ packed) {
    __shared__ float sz[256];
    int nf = *nflag;
    int t = threadIdx.x;
    int lane = t & 63, wv = t >> 6;
    for (int ii = blockIdx.x; ii < nf; ii += 64) {
        int n = list[ii];
        int b = n >> 10, hw = n & 1023;
        __syncthreads();
        sz[t] = z[(b * DD + t) * 1024 + hw];
        __syncthreads();
        float4 zr = ((const float4*)sz)[lane];
        double zqd = (double)zr.x * zr.x + (double)zr.y * zr.y
                   + (double)zr.z * zr.z + (double)zr.w * zr.w;
#pragma unroll
        for (int off = 32; off; off >>= 1) zqd += __shfl_xor(zqd, off, 64);
        float zq = (float)zqd;
        unsigned long long best = 0xFFFFFFFFFFFFFFFFull;
        int kbase = blockIdx.y * 256 + wv * 64;
        for (int j = 0; j < 64; ++j) {
            int k = kbase + j;
            float4 cc = *(const float4*)&cb[(size_t)k * DD + lane * 4];
            float p = (zr.x * cc.x + zr.y * cc.y) + (zr.z * cc.z + zr.w * cc.w);
#pragma unroll
            for (int off = 32; off; off >>= 1) p += __shfl_xor(p, off, 64);
            float dot = p / nrm[k];
            float dv = (zq + wsq[k]) - 2.0f * dot;
            unsigned bits = __float_as_uint(dv);
            bits = (bits & 0x80000000u) ? ~bits : (bits | 0x80000000u);
            unsigned long long pk = ((unsigned long long)bits << 32) | (unsigned)k;
            best = best < pk ? best : pk;
        }
        if (lane == 0) atomicMin(packed + n, best);
    }
}

// z_q gather (w = cb/nrm, identical rounding to prep) + loss partials;
// the d==0 slice also emits idx output + histogram.
__global__ __launch_bounds__(256) void gather_loss(
    const float* __restrict__ z, const float* __restrict__ cb,
    const float* __restrict__ nrm, const unsigned long long* __restrict__ packed,
    float* __restrict__ out, double* __restrict__ lossp, int* __restrict__ hist) {
    __shared__ double lred[4];
    int t = threadIdx.x;
    int base = (blockIdx.x * 256 + t) * 16;
    double s = 0.0;
#pragma unroll
    for (int q = 0; q < 4; ++q) {
        int e = base + q * 4;
        int b = e >> 18, d = (e >> 10) & 255, hw = e & 1023;
        int n = (b << 10) + hw;
        float4 zv = *(const float4*)&z[e];
        float o[4];
        int ks[4];
#pragma unroll
        for (int j = 0; j < 4; ++j) {
            ks[j] = (int)(packed[n + j] & 0xFFFFFFFFull);
            o[j] = cb[ks[j] * DD + d] / nrm[ks[j]];
        }
        *(float4*)&out[e] = make_float4(o[0], o[1], o[2], o[3]);
        if (d == 0) {
#pragma unroll
            for (int j = 0; j < 4; ++j) {
                out[ZQ_ELEMS + n + j] = (float)ks[j];
                atomicAdd(&hist[ks[j]], 1);
            }
        }
        float d0 = o[0] - zv.x, d1 = o[1] - zv.y, d2 = o[2] - zv.z, d3 = o[3] - zv.w;
        s += (double)(d0 * d0) + (double)(d1 * d1) + (double)(d2 * d2) + (double)(d3 * d3);
    }
    s = waveReduceD(s);
    int lane = t & 63, wid = t >> 6;
    if (lane == 0) lred[wid] = s;
    __syncthreads();
    if (t == 0) lossp[blockIdx.x] = lred[0] + lred[1] + lred[2] + lred[3];
}

// single block: loss from 512 partials + perplexity from histogram
__global__ __launch_bounds__(256) void finalize_kernel(
    const int* __restrict__ hist, const double* __restrict__ lossp,
    float* __restrict__ out) {
    __shared__ double lred[4];
    __shared__ double lsum;
    int t = threadIdx.x;
    int lane = t & 63, wid = t >> 6;
    double ls = lossp[t] + lossp[t + 256];
    ls = waveReduceD(ls);
    if (lane == 0) lred[wid] = ls;
    __syncthreads();
    if (t == 0) lsum = lred[0] + lred[1] + lred[2] + lred[3];
    __syncthreads();
    double s = 0.0;
    for (int i = t; i < KC; i += 256) {
        float p = (float)hist[i] * (1.0f / 8192.0f);
        float lg = logf(p + 1e-10f);
        s += (double)(p * lg);
    }
    s = waveReduceD(s);
    if (lane == 0) lred[wid] = s;
    __syncthreads();
    if (t == 0) {
        double tot = lred[0] + lred[1] + lred[2] + lred[3];
        float m = (float)(lsum / (double)ZQ_ELEMS);
        out[ZQ_ELEMS + NP] = m + 0.25f * m;
        out[ZQ_ELEMS + NP + 1] = expf(-(float)tot);
    }
}

extern "C" void kernel_launch(void* const* d_in, const int* in_sizes, int n_in,
                              void* d_out, int out_size, void* d_ws, size_t ws_size,
                              hipStream_t stream) {
    const float* z = (const float*)d_in[0];
    const float* cb = (const float*)d_in[1];
    float* out = (float*)d_out;
    char* ws = (char*)d_ws;

    unsigned short* Abig = (unsigned short*)(ws + OFF_ABIG);
    unsigned short* Bbig = (unsigned short*)(ws + OFF_BBIG);
    float* nrm = (float*)(ws + OFF_NRM);
    float* wsq = (float*)(ws + OFF_WSQ);
    float* pv1 = (float*)(ws + OFF_PV1);
    float* pv2 = (float*)(ws + OFF_PV2);
    int* pk1 = (int*)(ws + OFF_PK1);
    int* hist = (int*)(ws + OFF_HIST);
    double* lossp = (double*)(ws + OFF_LOSSP);
    unsigned long long* packed = (unsigned long long*)(ws + OFF_PACK);
    int* list = (int*)(ws + OFF_LIST);
    int* nflag = (int*)(ws + OFF_NFLG);

    prep<<<2560, 256, 0, stream>>>(cb, z, Bbig, Abig, nrm, wsq, hist, nflag);
    gemm_top2<<<dim3(32, NPART), 512, 0, stream>>>(Abig, Bbig, wsq, pv1, pv2, pk1);
    merge_top2<<<NP / 256, 256, 0, stream>>>(pv1, pv2, pk1, list, nflag, packed);
    rescore_par<<<dim3(64, 32), 256, 0, stream>>>(z, cb, nrm, wsq, list, nflag, packed);
    gather_loss<<<ZQ_ELEMS / (256 * 16), 256, 0, stream>>>(z, cb, nrm, packed, out, lossp, hist);
    finalize_kernel<<<1, 256, 0, stream>>>(hist, lossp, out);
}

// Round 18
// 292.972 us; speedup vs baseline: 1.0006x; 1.0006x over previous
//
#include <hip/hip_runtime.h>
#include <hip/hip_bf16.h>
#include <math.h>

// VectorQuantizer: z [8,256,32,32] f32, codebook [8192,256] f32
// outputs (flat f32): z_q [2097152] NCHW, idx [8192] (as float), loss, perplexity
#define KC 8192
#define DD 256
#define NP 8192
#define ZQ_ELEMS 2097152
#define MARGIN_S 1e-2f     // s-space (= 2e-2 d-space; fp16 E_max ~4.8e-3 d, 2x headroom)
#define NPART 8            // code-group partials (gemm grid.y)

// ws layout (bytes)
#define OFF_ABIG 0u           // f16 [8192][256]  points
#define OFF_BBIG 4194304u     // f16 [8192][256]  normalized codes
#define OFF_NRM  8388608u     // f32 [8192]
#define OFF_WSQ  8421376u     // f32 [8192]
#define OFF_PV1  8454144u     // f32 [8192][8]  (transposed partials)
#define OFF_PV2  8716288u     // f32 [8192][8]
#define OFF_PK1  8978432u     // i32 [8192][8]
#define OFF_LOSSP 9240576u    // f64 [512]
#define OFF_HIST 9244672u     // i32 [8192]
#define OFF_PACK 9277440u     // u64 [8192]
#define OFF_LIST 9342976u     // i32 [8192]
#define OFF_NFLG 9375744u     // i32 [1]

typedef __attribute__((ext_vector_type(8))) _Float16 f16x8;
typedef __attribute__((ext_vector_type(4))) float f32x4;
typedef __attribute__((address_space(3))) void as3_void;
typedef const __attribute__((address_space(1))) void as1_cvoid;

#define GLOAD16(g, l) __builtin_amdgcn_global_load_lds((as1_cvoid*)(g), (as3_void*)(l), 16, 0, 0)

__device__ inline double waveReduceD(double v) {
#pragma unroll
    for (int off = 32; off; off >>= 1) v += __shfl_down(v, off, 64);
    return v;
}

static __device__ inline unsigned short f2h(float f) {
    _Float16 h = (_Float16)f;  // RNE
    unsigned short u;
    __builtin_memcpy(&u, &h, 2);
    return u;
}

// fused prep:
//   blocks 0..2047: 4 codebook rows each (wave-per-row: normalize + f16 cast +
//                   wsq/nrm); blocks 0..31 zero hist; block 32 zeroes nflag
//   blocks 2048..2559: z tile-transpose (64d x 64hw, LDS-staged) + f16 cast
__global__ __launch_bounds__(256) void prep(
    const float* __restrict__ cb, const float* __restrict__ z,
    unsigned short* __restrict__ Bbig, unsigned short* __restrict__ Abig,
    float* __restrict__ nrm, float* __restrict__ wsq,
    int* __restrict__ hist, int* __restrict__ nflag) {
    int bid = blockIdx.x, t = threadIdx.x;
    int lane = t & 63, wid = t >> 6;
    if (bid < 2048) {
        if (bid < 32) hist[bid * 256 + t] = 0;
        if (bid == 32 && t == 0) *nflag = 0;
        int k = bid * 4 + wid;
        float4 c4 = *(const float4*)&cb[(size_t)k * DD + lane * 4];
        double s = (double)c4.x * c4.x + (double)c4.y * c4.y
                 + (double)c4.z * c4.z + (double)c4.w * c4.w;
#pragma unroll
        for (int off = 32; off; off >>= 1) s += __shfl_xor(s, off, 64);
        float mh = fmaxf(sqrtf((float)s), 1e-12f);
        if (lane == 0) {
            nrm[k] = mh;
            wsq[k] = (float)(s / ((double)mh * (double)mh));
        }
        *(ushort4*)&Bbig[(size_t)k * DD + lane * 4] =
            make_ushort4(f2h(c4.x / mh), f2h(c4.y / mh), f2h(c4.z / mh), f2h(c4.w / mh));
    } else {
        __shared__ float tile[64][65];
        int zb = bid - 2048;               // 0..511
        int b = zb >> 6, ht = (zb >> 2) & 15, dt = zb & 3;
        int hw0 = ht * 64, d0 = dt * 64;
#pragma unroll
        for (int i = 0; i < 16; ++i) {
            int dl = wid * 16 + i;
            tile[dl][lane] = z[(size_t)(b * DD + d0 + dl) * 1024 + hw0 + lane];
        }
        __syncthreads();
        // point row n = b*1024+hw0+nl needs z(d=d0+lane, hw=hw0+nl) == tile[lane][nl]
#pragma unroll
        for (int i = 0; i < 16; ++i) {
            int nl = wid * 16 + i;
            Abig[(size_t)(b * 1024 + hw0 + nl) * DD + d0 + lane] = f2h(tile[lane][nl]);
        }
    }
}

// Deep-pipelined MFMA GEMM + top-2 screen (R13 cadence, fp16 single-product).
// Quad-buffer, depth-3 staging, counted vmcnt, reg fragment ping-pong,
// 1 barrier/tile, single 32-tile sweep over 4 code-tiles (K=256 per ct).
// grid (32, 8) = 256 blocks = 1/CU. acc init = -wsq/2 => dv = -acc.
__global__ __launch_bounds__(512, 2) void gemm_top2(
    const unsigned short* __restrict__ Abig, const unsigned short* __restrict__ Bbig,
    const float* __restrict__ wsq,
    float* __restrict__ pv1, float* __restrict__ pv2, int* __restrict__ pk1) {
    __shared__ unsigned short sAB[65536];  // 4 bufs x [W 256x32 | Z 256x32] f16

    int t = threadIdx.x;
    int l = t & 63, w = t >> 6;
    int wm = w >> 2, wn = w & 3;
    int kc0 = blockIdx.y * 1024;  // this block's 1024-code range
    int n0 = blockIdx.x * 256;    // point base (C cols)

    int row0 = t >> 2;
    int lsw = (((t & 3) ^ ((row0 >> 1) & 3)) << 3);
    int subsw = (((l >> 4) ^ ((l >> 1) & 3)) << 3);

#define STAGE(g_) do {                                                         \
    int ct_ = (g_) >> 3;                                                       \
    int kt_ = (g_) & 7;                                                        \
    int off_ = kt_ * 32;                                                       \
    int b_ = ((g_) & 3) * 16384;                                               \
    int kc_ = kc0 + ct_ * 256;                                                 \
    GLOAD16(Bbig + (size_t)(kc_ + row0) * 256 + off_ + lsw, &sAB[b_ + t * 8]); \
    GLOAD16(Bbig + (size_t)(kc_ + row0 + 128) * 256 + off_ + lsw, &sAB[b_ + 4096 + t * 8]); \
    GLOAD16(Abig + (size_t)(n0 + row0) * 256 + off_ + lsw, &sAB[b_ + 8192 + t * 8]); \
    GLOAD16(Abig + (size_t)(n0 + row0 + 128) * 256 + off_ + lsw, &sAB[b_ + 12288 + t * 8]); \
} while (0)

#define LDFRAG(bufbase, fa, fb) do {                                           \
    _Pragma("unroll")                                                          \
    for (int mf = 0; mf < 8; ++mf)                                             \
        fa[mf] = *(const f16x8*)&sAB[(bufbase) + (wm * 128 + mf * 16 + (l & 15)) * 32 + subsw]; \
    _Pragma("unroll")                                                          \
    for (int nf = 0; nf < 4; ++nf)                                             \
        fb[nf] = *(const f16x8*)&sAB[(bufbase) + 8192 + (wn * 64 + nf * 16 + (l & 15)) * 32 + subsw]; \
} while (0)

#define MFMACL(fa, fb) do {                                                    \
    __builtin_amdgcn_s_setprio(1);                                             \
    _Pragma("unroll")                                                          \
    for (int mf = 0; mf < 8; ++mf)                                             \
        _Pragma("unroll")                                                      \
        for (int nf = 0; nf < 4; ++nf)                                         \
            acc[mf][nf] = __builtin_amdgcn_mfma_f32_16x16x32_f16(fa[mf], fb[nf], acc[mf][nf], 0, 0, 0); \
    __builtin_amdgcn_s_setprio(0);                                             \
} while (0)

#define WAITBAR(n_) do {                                                       \
    asm volatile("s_waitcnt vmcnt(" #n_ ")" ::: "memory");                     \
    __builtin_amdgcn_s_barrier();                                              \
    asm volatile("" ::: "memory");                                             \
} while (0)

#define RESETACC(ct_) do {                                                     \
    _Pragma("unroll")                                                          \
    for (int mf = 0; mf < 8; ++mf) {                                           \
        _Pragma("unroll")                                                      \
        for (int r = 0; r < 4; ++r) {                                          \
            float hv = -0.5f * wsq[kc0 + (ct_) * 256 + wm * 128 + mf * 16 + ((l >> 4) << 2) + r]; \
            _Pragma("unroll")                                                  \
            for (int nf = 0; nf < 4; ++nf) acc[mf][nf][r] = hv;                \
        }                                                                      \
    }                                                                          \
} while (0)

#define EXTRACT(ct_) do {                                                      \
    _Pragma("unroll")                                                          \
    for (int mf = 0; mf < 8; ++mf) {                                           \
        _Pragma("unroll")                                                      \
        for (int r = 0; r < 4; ++r) {                                          \
            int code = kc0 + (ct_) * 256 + wm * 128 + mf * 16 + ((l >> 4) << 2) + r; \
            _Pragma("unroll")                                                  \
            for (int nf = 0; nf < 4; ++nf) {                                   \
                float dv = -acc[mf][nf][r];                                    \
                bool lt = dv < v1[nf];                                         \
                v2[nf] = fminf(v2[nf], fmaxf(v1[nf], dv));                     \
                v1[nf] = fminf(v1[nf], dv);                                    \
                k1[nf] = lt ? code : k1[nf];                                   \
            }                                                                  \
        }                                                                      \
    }                                                                          \
} while (0)

    float v1[4], v2[4];
    int k1[4];
#pragma unroll
    for (int nf = 0; nf < 4; ++nf) { v1[nf] = 3.4e38f; v2[nf] = 3.4e38f; k1[nf] = 0; }

    f32x4 acc[8][4];
    RESETACC(0);

    f16x8 fa0[8], fb0[4], fa1[8], fb1[4];

    // prologue: stage tiles 0,1,2; tile 0 resident (8 loads stay in flight)
    STAGE(0);
    STAGE(1);
    STAGE(2);
    WAITBAR(8);
    LDFRAG(0, fa0, fb0);

    // 32-tile loop (tiles 0..29 here; 30,31 in tail). Boundary extracts at
    // tile 7/15/23 (ct 0/1/2); ct 3 extracted in tail.
    for (int g = 0; g < 30; g += 2) {
        WAITBAR(4);                               // tile g+1 resident
        LDFRAG(((g + 1) & 3) * 16384, fa1, fb1);
        STAGE(g + 3);                             // g <= 28 -> g+3 <= 31
        MFMACL(fa0, fb0);                         // tile g
        WAITBAR(4);                               // tile g+2 resident
        LDFRAG(((g + 2) & 3) * 16384, fa0, fb0);
        if (g < 28) STAGE(g + 4);
        MFMACL(fa1, fb1);                         // tile g+1
        if (((g + 1) & 7) == 7) {
            int ct = (g + 1) >> 3;
            EXTRACT(ct);
            RESETACC(ct + 1);                     // ct < 3 always here
        }
    }
    // tail: tiles 30, 31
    WAITBAR(0);                                   // tile 31 resident
    LDFRAG(3 * 16384, fa1, fb1);
    MFMACL(fa0, fb0);                             // tile 30
    MFMACL(fa1, fb1);                             // tile 31
    EXTRACT(3);

    // merge across the 4 row-groups (lanes l, l^16, l^32, l^48 share cols)
#pragma unroll
    for (int nf = 0; nf < 4; ++nf) {
#pragma unroll
        for (int mask = 16; mask <= 32; mask <<= 1) {
            float ov1 = __shfl_xor(v1[nf], mask, 64);
            float ov2 = __shfl_xor(v2[nf], mask, 64);
            int ok1 = __shfl_xor(k1[nf], mask, 64);
            bool take = (ov1 < v1[nf]) || (ov1 == v1[nf] && ok1 < k1[nf]);
            if (take) { v2[nf] = fminf(v1[nf], ov2); v1[nf] = ov1; k1[nf] = ok1; }
            else v2[nf] = fminf(v2[nf], ov1);
        }
    }
    __syncthreads();  // pipeline fully done; reuse LDS for cross-wave merge
    float* sv1 = (float*)sAB;            // [256][2]
    float* sv2 = sv1 + 512;
    int* sk1 = (int*)(sv2 + 512);
    if ((l >> 4) == 0) {
#pragma unroll
        for (int nf = 0; nf < 4; ++nf) {
            int col = wn * 64 + nf * 16 + l;
            sv1[col * 2 + wm] = v1[nf];
            sv2[col * 2 + wm] = v2[nf];
            sk1[col * 2 + wm] = k1[nf];
        }
    }
    __syncthreads();
    if (t < 256) {
        float a1 = sv1[t * 2], b1 = sv1[t * 2 + 1];
        float a2 = sv2[t * 2], b2 = sv2[t * 2 + 1];
        int ak = sk1[t * 2], bk = sk1[t * 2 + 1];
        bool tb = (b1 < a1) || (b1 == a1 && bk < ak);
        float w1 = tb ? b1 : a1;
        int wk = tb ? bk : ak;
        float w2 = tb ? fminf(b2, a1) : fminf(a2, b1);
        pv1[(size_t)(n0 + t) * NPART + blockIdx.y] = w1;
        pv2[(size_t)(n0 + t) * NPART + blockIdx.y] = w2;
        pk1[(size_t)(n0 + t) * NPART + blockIdx.y] = wk;
    }
#undef STAGE
#undef LDFRAG
#undef MFMACL
#undef WAITBAR
#undef RESETACC
#undef EXTRACT
}

// merge 8 partials per point (contiguous); packed holds winner k (or ~0
// sentinel for flagged rows, which rescore_par atomicMin-fills exactly)
__global__ __launch_bounds__(256) void merge_top2(
    const float* __restrict__ pv1, const float* __restrict__ pv2,
    const int* __restrict__ pk1, int* __restrict__ list, int* __restrict__ nflag,
    unsigned long long* __restrict__ packed) {
    int n = blockIdx.x * 256 + threadIdx.x;
    float gv1 = 3.4e38f, gv2 = 3.4e38f;
    int gk1 = 0;
#pragma unroll
    for (int ct = 0; ct < NPART; ++ct) {
        float v1 = pv1[(size_t)n * NPART + ct];
        if (v1 < gv1) {
            gv2 = fminf(gv1, pv2[(size_t)n * NPART + ct]);
            gv1 = v1;
            gk1 = pk1[(size_t)n * NPART + ct];
        } else {
            gv2 = fminf(gv2, v1);
        }
    }
    int f = (gv2 - gv1 < MARGIN_S) ? 1 : 0;
    packed[n] = f ? 0xFFFFFFFFFFFFFFFFull : (unsigned long long)(unsigned)gk1;
    if (f) {
        int pos = atomicAdd(nflag, 1);
        list[pos] = n;
    }
}

// exact fp32 rescore of flagged rows, wave-cooperative (lanes along D).
__global__ __launch_bounds__(256) void rescore_par(
    const float* __restrict__ z, const float* __restrict__ cb,
    const float* __restrict__ nrm, const float* __restrict__ wsq,
    const int* __restrict__ list, const int* __restrict__ nflag,
    unsigned long long* __restrict__ packed) {
    __shared__ float sz[256];
    int nf = *nflag;
    int t = threadIdx.x;
    int lane = t & 63, wv = t >> 6;
    for (int ii = blockIdx.x; ii < nf; ii += 64) {
        int n = list[ii];
        int b = n >> 10, hw = n & 1023;
        __syncthreads();
        sz[t] = z[(b * DD + t) * 1024 + hw];
        __syncthreads();
        float4 zr = ((const float4*)sz)[lane];
        double zqd = (double)zr.x * zr.x + (double)zr.y * zr.y
                   + (double)zr.z * zr.z + (double)zr.w * zr.w;
#pragma unroll
        for (int off = 32; off; off >>= 1) zqd += __shfl_xor(zqd, off, 64);
        float zq = (float)zqd;
        unsigned long long best = 0xFFFFFFFFFFFFFFFFull;
        int kbase = blockIdx.y * 256 + wv * 64;
        for (int j = 0; j < 64; ++j) {
            int k = kbase + j;
            float4 cc = *(const float4*)&cb[(size_t)k * DD + lane * 4];
            float p = (zr.x * cc.x + zr.y * cc.y) + (zr.z * cc.z + zr.w * cc.w);
#pragma unroll
            for (int off = 32; off; off >>= 1) p += __shfl_xor(p, off, 64);
            float dot = p / nrm[k];
            float dv = (zq + wsq[k]) - 2.0f * dot;
            unsigned bits = __float_as_uint(dv);
            bits = (bits & 0x80000000u) ? ~bits : (bits | 0x80000000u);
            unsigned long long pk = ((unsigned long long)bits << 32) | (unsigned)k;
            best = best < pk ? best : pk;
        }
        if (lane == 0) atomicMin(packed + n, best);
    }
}

// z_q gather (w = cb/nrm, identical rounding to prep) + loss partials;
// the d==0 slice also emits idx output + histogram.
__global__ __launch_bounds__(256) void gather_loss(
    const float* __restrict__ z, const float* __restrict__ cb,
    const float* __restrict__ nrm, const unsigned long long* __restrict__ packed,
    float* __restrict__ out, double* __restrict__ lossp, int* __restrict__ hist) {
    __shared__ double lred[4];
    int t = threadIdx.x;
    int base = (blockIdx.x * 256 + t) * 16;
    double s = 0.0;
#pragma unroll
    for (int q = 0; q < 4; ++q) {
        int e = base + q * 4;
        int b = e >> 18, d = (e >> 10) & 255, hw = e & 1023;
        int n = (b << 10) + hw;
        float4 zv = *(const float4*)&z[e];
        float o[4];
        int ks[4];
#pragma unroll
        for (int j = 0; j < 4; ++j) {
            ks[j] = (int)(packed[n + j] & 0xFFFFFFFFull);
            o[j] = cb[ks[j] * DD + d] / nrm[ks[j]];
        }
        *(float4*)&out[e] = make_float4(o[0], o[1], o[2], o[3]);
        if (d == 0) {
#pragma unroll
            for (int j = 0; j < 4; ++j) {
                out[ZQ_ELEMS + n + j] = (float)ks[j];
                atomicAdd(&hist[ks[j]], 1);
            }
        }
        float d0 = o[0] - zv.x, d1 = o[1] - zv.y, d2 = o[2] - zv.z, d3 = o[3] - zv.w;
        s += (double)(d0 * d0) + (double)(d1 * d1) + (double)(d2 * d2) + (double)(d3 * d3);
    }
    s = waveReduceD(s);
    int lane = t & 63, wid = t >> 6;
    if (lane == 0) lred[wid] = s;
    __syncthreads();
    if (t == 0) lossp[blockIdx.x] = lred[0] + lred[1] + lred[2] + lred[3];
}

// single block: loss from 512 partials + perplexity from histogram
__global__ __launch_bounds__(256) void finalize_kernel(
    const int* __restrict__ hist, const double* __restrict__ lossp,
    float* __restrict__ out) {
    __shared__ double lred[4];
    __shared__ double lsum;
    int t = threadIdx.x;
    int lane = t & 63, wid = t >> 6;
    double ls = lossp[t] + lossp[t + 256];
    ls = waveReduceD(ls);
    if (lane == 0) lred[wid] = ls;
    __syncthreads();
    if (t == 0) lsum = lred[0] + lred[1] + lred[2] + lred[3];
    __syncthreads();
    double s = 0.0;
    for (int i = t; i < KC; i += 256) {
        float p = (float)hist[i] * (1.0f / 8192.0f);
        float lg = logf(p + 1e-10f);
        s += (double)(p * lg);
    }
    s = waveReduceD(s);
    if (lane == 0) lred[wid] = s;
    __syncthreads();
    if (t == 0) {
        double tot = lred[0] + lred[1] + lred[2] + lred[3];
        float m = (float)(lsum / (double)ZQ_ELEMS);
        out[ZQ_ELEMS + NP] = m + 0.25f * m;
        out[ZQ_ELEMS + NP + 1] = expf(-(float)tot);
    }
}

extern "C" void kernel_launch(void* const* d_in, const int* in_sizes, int n_in,
                              void* d_out, int out_size, void* d_ws, size_t ws_size,
                              hipStream_t stream) {
    const float* z = (const float*)d_in[0];
    const float* cb = (const float*)d_in[1];
    float* out = (float*)d_out;
    char* ws = (char*)d_ws;

    unsigned short* Abig = (unsigned short*)(ws + OFF_ABIG);
    unsigned short* Bbig = (unsigned short*)(ws + OFF_BBIG);
    float* nrm = (float*)(ws + OFF_NRM);
    float* wsq = (float*)(ws + OFF_WSQ);
    float* pv1 = (float*)(ws + OFF_PV1);
    float* pv2 = (float*)(ws + OFF_PV2);
    int* pk1 = (int*)(ws + OFF_PK1);
    int* hist = (int*)(ws + OFF_HIST);
    double* lossp = (double*)(ws + OFF_LOSSP);
    unsigned long long* packed = (unsigned long long*)(ws + OFF_PACK);
    int* list = (int*)(ws + OFF_LIST);
    int* nflag = (int*)(ws + OFF_NFLG);

    prep<<<2560, 256, 0, stream>>>(cb, z, Bbig, Abig, nrm, wsq, hist, nflag);
    gemm_top2<<<dim3(32, NPART), 512, 0, stream>>>(Abig, Bbig, wsq, pv1, pv2, pk1);
    merge_top2<<<NP / 256, 256, 0, stream>>>(pv1, pv2, pk1, list, nflag, packed);
    rescore_par<<<dim3(64, 32), 256, 0, stream>>>(z, cb, nrm, wsq, list, nflag, packed);
    gather_loss<<<ZQ_ELEMS / (256 * 16), 256, 0, stream>>>(z, cb, nrm, packed, out, lossp, hist);
    finalize_kernel<<<1, 256, 0, stream>>>(hist, lossp, out);
}